// Round 10
// baseline (54.963 us; speedup 1.0000x reference)
//
#include <hip/hip_runtime.h>
#include <math.h>

namespace {
constexpr int L = 7, S = 200, SE = 240, D = 32, B = 512;
constexpr int NTOK = L * B;      // 3584
constexpr int NBLK = NTOK / 4;   // 896 blocks, 4 waves, one token per wave

// ---- cross-lane helpers: DPP (VALU-speed), DS only for xor16 (proven R8/R9) ----
template <int CTRL>
__device__ __forceinline__ float dppf(float x) {
  return __int_as_float(__builtin_amdgcn_update_dpp(
      0, __float_as_int(x), CTRL, 0xF, 0xF, true));
}
template <int CTRL>
__device__ __forceinline__ int dppi(int x) {
  return __builtin_amdgcn_update_dpp(0, x, CTRL, 0xF, 0xF, true);
}
// quad_perm[1,0,3,2]=0xB1 (xor1), quad_perm[2,3,0,1]=0x4E (xor2),
// row_half_mirror=0x141 (lane^7 in 16 => other quad), row_ror:8=0x128 (lane^8 in 16).
__device__ __forceinline__ float swz16f(float x) {  // lane^16 (within 32)
  return __int_as_float(__builtin_amdgcn_ds_swizzle(__float_as_int(x), 0x401F));
}
__device__ __forceinline__ int swz16i(int x) {
  return __builtin_amdgcn_ds_swizzle(x, 0x401F);
}

// ---- single-node kernel: one wave per token, zero cross-block dependencies ----
// Phase 1: 200 dots vs centroids (coalesced 8-row chunks, DPP octet reduce),
//          exact top-3 (jax tie-break: desc value, lower index), softmax.
// Phase 2: for each of the 3 selected clusters, compose its parameter vector
//          directly (sigmoid-weights -> LDS, then the R9 compose inner loop),
//          xor-reduce, accumulate p_k * cluster_sum, write out.
// Redundant vec reads (avg 7.7 tokens/cluster) are served by L2/L3; the XCD-aware
// token swizzle keeps each XCD's hot-set to ~1 layer (~7 MB).
__global__ __launch_bounds__(256) void fused_kernel(
    const float* __restrict__ x,     // [L,B,D]
    const float* __restrict__ vc,    // [L,S,D]
    const float* __restrict__ vec,   // [L,S,SE,D]
    const float* __restrict__ gain,  // [L,S,SE,2]
    const int* __restrict__ blk,     // [L,S,SE,2]
    float* __restrict__ out)         // [L,B,D]
{
  const int wave = threadIdx.x >> 6;
  const int lane = threadIdx.x & 63;
  // XCD-aware swizzle: blocks b with b&7==x run on XCD x (round-robin dispatch);
  // slot = (b&7)*112 + b>>3 gives XCD x the contiguous token range [x*448,(x+1)*448)
  // -> each XCD touches <= 2 layers' vec (~7-12 MB hot-set vs 49 MB unswizzled).
  const int slot = (blockIdx.x & 7) * (NBLK / 8) + (blockIdx.x >> 3);
  const int tok = slot * 4 + wave;
  const int l = tok >> 9;  // B = 512
  const int q = lane & 7;  // float4 column [0,8)
  const int r8 = lane >> 3;

  __shared__ float w[4][SE];  // wave-private weight rows (broadcast reads)

  // ---------------- phase 1: router ----------------
  const float4 xq = reinterpret_cast<const float4*>(x + tok * D)[q];  // one 128B line
  const float* vcl = vc + l * S * D;

  float v0 = -INFINITY, v1 = -INFINITY, v2 = -INFINITY;
  int i0 = 0x7fffffff, i1 = 0x7fffffff, i2 = 0x7fffffff;
  for (int s0 = 0; s0 < S; s0 += 8) {  // 25 chunks; wave reads 8 rows x 128B contiguous
    const int row = s0 + r8;
    const float4 v = reinterpret_cast<const float4*>(vcl + row * D)[q];
    float part = v.x * xq.x + v.y * xq.y + v.z * xq.z + v.w * xq.w;
    part += dppf<0xB1>(part);   // xor1 (quad_perm)
    part += dppf<0x4E>(part);   // xor2 (quad_perm)
    part += dppf<0x141>(part);  // other quad of octet (quads uniform after xor1/2)
    // all 8 lanes of octet r8 hold the dot for `row`; insert on all lanes
    if (part > v0) { v2 = v1; i2 = i1; v1 = v0; i1 = i0; v0 = part; i0 = row; }
    else if (part > v1) { v2 = v1; i2 = i1; v1 = part; i1 = row; }
    else if (part > v2) { v2 = part; i2 = row; }
  }
  // 3-step merge across octets (partners hold disjoint row residues)
#pragma unroll
  for (int step = 0; step < 3; ++step) {
    float u0, u1, u2; int j0, j1, j2;
    if (step == 0) {
      u0 = dppf<0x128>(v0); u1 = dppf<0x128>(v1); u2 = dppf<0x128>(v2);
      j0 = dppi<0x128>(i0); j1 = dppi<0x128>(i1); j2 = dppi<0x128>(i2);
    } else if (step == 1) {
      u0 = swz16f(v0); u1 = swz16f(v1); u2 = swz16f(v2);
      j0 = swz16i(i0); j1 = swz16i(i1); j2 = swz16i(i2);
    } else {
      u0 = __shfl_xor(v0, 32); u1 = __shfl_xor(v1, 32); u2 = __shfl_xor(v2, 32);
      j0 = __shfl_xor(i0, 32); j1 = __shfl_xor(i1, 32); j2 = __shfl_xor(i2, 32);
    }
#pragma unroll
    for (int t = 0; t < 3; ++t) {  // jax tie-break: desc value, lower index
      const float u = (t == 0) ? u0 : (t == 1) ? u1 : u2;
      const int j = (t == 0) ? j0 : (t == 1) ? j1 : j2;
      const bool b0 = (u > v0) || (u == v0 && j < i0);
      const bool b1 = (u > v1) || (u == v1 && j < i1);
      const bool b2 = (u > v2) || (u == v2 && j < i2);
      if (b0) { v2 = v1; i2 = i1; v1 = v0; i1 = i0; v0 = u; i0 = j; }
      else if (b1) { v2 = v1; i2 = i1; v1 = u; i1 = j; }
      else if (b2) { v2 = u; i2 = j; }
    }
  }
  const float e1 = __expf(v1 - v0);
  const float e2 = __expf(v2 - v0);
  const float sinv = 1.f / (1.f + e1 + e2);
  const float p0 = sinv, p1 = e1 * sinv, p2 = e2 * sinv;

  // ---------------- phase 2: direct compose of the 3 selected clusters ----------------
  float4 oacc = make_float4(0.f, 0.f, 0.f, 0.f);
#pragma unroll
  for (int k = 0; k < 3; ++k) {
    const int sk = (k == 0) ? i0 : (k == 1) ? i1 : i2;
    const float pk = (k == 0) ? p0 : (k == 1) ? p1 : p2;
    const int ls = l * S + sk;
    // sigmoid weights for this cluster -> wave-private LDS (coalesced 8B loads)
    for (int e = lane; e < SE; e += 64) {
      const float2 g2 = reinterpret_cast<const float2*>(gain)[ls * SE + e];
      const int2 b2 = reinterpret_cast<const int2*>(blk)[ls * SE + e];
      w[wave][e] = (b2.x != 0) ? 1.0f / (1.0f + __expf(-g2.x)) : 0.0f;
    }
    // in-wave LDS write->read: compiler inserts lgkmcnt (same array, program order)
    const float4* v4 = reinterpret_cast<const float4*>(vec) + (size_t)ls * SE * 8;
    float4 acc = make_float4(0.f, 0.f, 0.f, 0.f);
#pragma unroll 10
    for (int kk = 0; kk < 30; ++kk) {  // wave reads 8 rows x 128B = 1KB contiguous
      const int e = kk * 8 + r8;
      const float we = w[wave][e];
      const float4 v = v4[e * 8 + q];
      acc.x += we * v.x; acc.y += we * v.y; acc.z += we * v.z; acc.w += we * v.w;
    }
    // reduce over r8 (lane bits 3,4,5): xor8 DPP, xor16 swizzle, xor32 shfl
    acc.x += dppf<0x128>(acc.x); acc.y += dppf<0x128>(acc.y);
    acc.z += dppf<0x128>(acc.z); acc.w += dppf<0x128>(acc.w);
    acc.x += swz16f(acc.x); acc.y += swz16f(acc.y);
    acc.z += swz16f(acc.z); acc.w += swz16f(acc.w);
    acc.x += __shfl_xor(acc.x, 32); acc.y += __shfl_xor(acc.y, 32);
    acc.z += __shfl_xor(acc.z, 32); acc.w += __shfl_xor(acc.w, 32);
    oacc.x += pk * acc.x; oacc.y += pk * acc.y;
    oacc.z += pk * acc.z; oacc.w += pk * acc.w;
  }
  if (lane < 8)  // lanes 0-7 hold q=0-7; 8 x 16B = 128B coalesced token row
    reinterpret_cast<float4*>(out + tok * D)[lane] = oacc;
}

}  // namespace

extern "C" void kernel_launch(void* const* d_in, const int* in_sizes, int n_in,
                              void* d_out, int out_size, void* d_ws, size_t ws_size,
                              hipStream_t stream) {
  const float* x = (const float*)d_in[0];      // [L,B,D]
  const float* vc = (const float*)d_in[1];     // [L,S,D]
  const float* vec = (const float*)d_in[2];    // [L,S,SE,D]
  const float* gain = (const float*)d_in[3];   // [L,S,SE,2]
  const int* blk = (const int*)d_in[4];        // [L,S,SE,2]
  float* out = (float*)d_out;                  // [L,B,D]

  fused_kernel<<<NBLK, 256, 0, stream>>>(x, vc, vec, gain, blk, out);
}

// Round 11
// 26.535 us; speedup vs baseline: 2.0714x; 2.0714x over previous
//
#include <hip/hip_runtime.h>
#include <math.h>

namespace {
constexpr int L = 7, S = 200, SE = 240, D = 32, B = 512;
constexpr int NTOK = L * B;      // 3584
constexpr int NCLUST = L * S;    // 1400
constexpr int GRID1 = NCLUST + NTOK;  // 4984 one-wave blocks, compose first

// ---- cross-lane helpers: DPP (VALU-speed), DS only for xor16 (proven R8/R9) ----
template <int CTRL>
__device__ __forceinline__ float dppf(float x) {
  return __int_as_float(__builtin_amdgcn_update_dpp(
      0, __float_as_int(x), CTRL, 0xF, 0xF, true));
}
template <int CTRL>
__device__ __forceinline__ int dppi(int x) {
  return __builtin_amdgcn_update_dpp(0, x, CTRL, 0xF, 0xF, true);
}
// quad_perm[1,0,3,2]=0xB1 (xor1), quad_perm[2,3,0,1]=0x4E (xor2),
// row_half_mirror=0x141 (lane^7 in 16 => other quad), row_ror:8=0x128 (lane^8 in 16).
__device__ __forceinline__ float swz16f(float x) {  // lane^16 (within 32)
  return __int_as_float(__builtin_amdgcn_ds_swizzle(__float_as_int(x), 0x401F));
}
__device__ __forceinline__ int swz16i(int x) {
  return __builtin_amdgcn_ds_swizzle(x, 0x401F);
}

// ---------------- node 1: one WAVE per block (64 thr), wave-granular balance ----------------
// Blocks [0, NCLUST): compose C[ls,:] (31KB stream each). Dispatched first.
// Blocks [NCLUST, GRID1): route one token -> (tki, tkp). Light; fills CU gaps.
// Round-robin dispatch => every CU gets ~5.5 compose waves + ~14 route waves;
// worst-case tail is one extra 31KB wave (~18%), vs 2x whole blocks in R9.
__global__ __launch_bounds__(64) void fused1_kernel(
    const float* __restrict__ x,     // [L,B,D]
    const float* __restrict__ vc,    // [L,S,D]
    const float* __restrict__ vec,   // [L,S,SE,D]
    const float* __restrict__ gain,  // [L,S,SE,2]
    const int* __restrict__ blk,     // [L,S,SE,2]
    float* __restrict__ C,           // [L*S, D] ws
    int4* __restrict__ tki,          // [NTOK] ws
    float4* __restrict__ tkp)        // [NTOK] ws
{
  const int lane = threadIdx.x;
  const int q = lane & 7;   // float4 column [0,8)
  const int r8 = lane >> 3; // octet / e-row group [0,8)

  if (blockIdx.x < NCLUST) {
    // ---- compose: this wave owns cluster ls ----
    const int ls = blockIdx.x;
    __shared__ float sw[SE];
    for (int e = lane; e < SE; e += 64) {
      const float2 g2 = reinterpret_cast<const float2*>(gain)[ls * SE + e];  // 8B coalesced
      const int2 b2 = reinterpret_cast<const int2*>(blk)[ls * SE + e];
      sw[e] = (b2.x != 0) ? 1.0f / (1.0f + __expf(-g2.x)) : 0.0f;
    }
    __syncthreads();  // single-wave block: compiles to a waitcnt
    const float4* v4 = reinterpret_cast<const float4*>(vec) + (size_t)ls * SE * 8;
    float4 acc = make_float4(0.f, 0.f, 0.f, 0.f);
#pragma unroll 10
    for (int k = 0; k < 30; ++k) {  // wave reads 8 rows x 128B = 1KB contiguous per step
      const int e = k * 8 + r8;
      const float we = sw[e];
      const float4 v = v4[e * 8 + q];
      acc.x += we * v.x; acc.y += we * v.y; acc.z += we * v.z; acc.w += we * v.w;
    }
    // reduce over r8 (lane bits 3,4,5): xor8 DPP, xor16 swizzle, xor32 shfl
    acc.x += dppf<0x128>(acc.x); acc.y += dppf<0x128>(acc.y);
    acc.z += dppf<0x128>(acc.z); acc.w += dppf<0x128>(acc.w);
    acc.x += swz16f(acc.x); acc.y += swz16f(acc.y);
    acc.z += swz16f(acc.z); acc.w += swz16f(acc.w);
    acc.x += __shfl_xor(acc.x, 32); acc.y += __shfl_xor(acc.y, 32);
    acc.z += __shfl_xor(acc.z, 32); acc.w += __shfl_xor(acc.w, 32);
    if (r8 == 0) reinterpret_cast<float4*>(C + ls * D)[q] = acc;
  } else {
    // ---- route-A: this wave owns one token (R8/R9-proven DPP path) ----
    const int tok = blockIdx.x - NCLUST;
    const int l = tok >> 9;  // B = 512

    const float4 xq = reinterpret_cast<const float4*>(x + tok * D)[q];  // one 128B line
    const float* vcl = vc + l * S * D;

    float v0 = -INFINITY, v1 = -INFINITY, v2 = -INFINITY;
    int i0 = 0x7fffffff, i1 = 0x7fffffff, i2 = 0x7fffffff;
    for (int s0 = 0; s0 < S; s0 += 8) {  // 25 chunks; 8 rows x 128B contiguous per wave
      const int row = s0 + r8;
      const float4 v = reinterpret_cast<const float4*>(vcl + row * D)[q];
      float part = v.x * xq.x + v.y * xq.y + v.z * xq.z + v.w * xq.w;
      part += dppf<0xB1>(part);   // xor1 (quad_perm)
      part += dppf<0x4E>(part);   // xor2 (quad_perm)
      part += dppf<0x141>(part);  // other quad of octet (quads uniform after xor1/2)
      // all 8 lanes of octet r8 hold the dot for `row`; insert on all lanes
      if (part > v0) { v2 = v1; i2 = i1; v1 = v0; i1 = i0; v0 = part; i0 = row; }
      else if (part > v1) { v2 = v1; i2 = i1; v1 = part; i1 = row; }
      else if (part > v2) { v2 = part; i2 = row; }
    }
    // 3-step merge across octets (partners hold disjoint row residues)
#pragma unroll
    for (int step = 0; step < 3; ++step) {
      float u0, u1, u2; int j0, j1, j2;
      if (step == 0) {
        u0 = dppf<0x128>(v0); u1 = dppf<0x128>(v1); u2 = dppf<0x128>(v2);
        j0 = dppi<0x128>(i0); j1 = dppi<0x128>(i1); j2 = dppi<0x128>(i2);
      } else if (step == 1) {
        u0 = swz16f(v0); u1 = swz16f(v1); u2 = swz16f(v2);
        j0 = swz16i(i0); j1 = swz16i(i1); j2 = swz16i(i2);
      } else {
        u0 = __shfl_xor(v0, 32); u1 = __shfl_xor(v1, 32); u2 = __shfl_xor(v2, 32);
        j0 = __shfl_xor(i0, 32); j1 = __shfl_xor(i1, 32); j2 = __shfl_xor(i2, 32);
      }
#pragma unroll
      for (int t = 0; t < 3; ++t) {  // jax tie-break: desc value, lower index
        const float u = (t == 0) ? u0 : (t == 1) ? u1 : u2;
        const int j = (t == 0) ? j0 : (t == 1) ? j1 : j2;
        const bool b0 = (u > v0) || (u == v0 && j < i0);
        const bool b1 = (u > v1) || (u == v1 && j < i1);
        const bool b2 = (u > v2) || (u == v2 && j < i2);
        if (b0) { v2 = v1; i2 = i1; v1 = v0; i1 = i0; v0 = u; i0 = j; }
        else if (b1) { v2 = v1; i2 = i1; v1 = u; i1 = j; }
        else if (b2) { v2 = u; i2 = j; }
      }
    }
    if (lane == 0) {
      const float e1 = __expf(v1 - v0);
      const float e2 = __expf(v2 - v0);
      const float inv = 1.f / (1.f + e1 + e2);
      tki[tok] = make_int4(i0, i1, i2, 0);
      tkp[tok] = make_float4(inv, e1 * inv, e2 * inv, 0.f);
    }
  }
}

// ---------------- node 2: gather. Thread per (token, d). ----------------
__global__ __launch_bounds__(256) void gather_kernel(
    const float* __restrict__ C,      // [L*S, D]
    const int4* __restrict__ tki,     // [NTOK]
    const float4* __restrict__ tkp,   // [NTOK]
    float* __restrict__ out)          // [L,B,D]
{
  const int gid = blockIdx.x * 256 + threadIdx.x;  // 448 blocks * 256 = NTOK*D
  const int tok = gid >> 5;
  const int d = gid & 31;
  const int l = tok >> 9;
  const int4 id = tki[tok];
  const float4 p = tkp[tok];
  const float* Cl = C + l * S * D;
  out[gid] = p.x * Cl[id.x * D + d] + p.y * Cl[id.y * D + d] + p.z * Cl[id.z * D + d];
}

}  // namespace

extern "C" void kernel_launch(void* const* d_in, const int* in_sizes, int n_in,
                              void* d_out, int out_size, void* d_ws, size_t ws_size,
                              hipStream_t stream) {
  const float* x = (const float*)d_in[0];      // [L,B,D]
  const float* vc = (const float*)d_in[1];     // [L,S,D]
  const float* vec = (const float*)d_in[2];    // [L,S,SE,D]
  const float* gain = (const float*)d_in[3];   // [L,S,SE,2]
  const int* blk = (const int*)d_in[4];        // [L,S,SE,2]
  float* out = (float*)d_out;                  // [L,B,D]

  char* ws = (char*)d_ws;
  float* C = (float*)ws;                          // 179,200 B
  int4* tki = (int4*)(ws + 179200);               // 57,344 B (16B aligned)
  float4* tkp = (float4*)(ws + 179200 + 57344);   // 57,344 B

  fused1_kernel<<<GRID1, 64, 0, stream>>>(x, vc, vec, gain, blk, C, tki, tkp);
  gather_kernel<<<NTOK * D / 256, 256, 0, stream>>>(C, tki, tkp, out);
}